// Round 4
// baseline (273.433 us; speedup 1.0000x reference)
//
#include <hip/hip_runtime.h>

#define HW   128
#define OHW  256
#define G0n  64
#define HID  256
#define NOUT 1728
#define NB   4

typedef __attribute__((ext_vector_type(8))) short bf16x8;
typedef __attribute__((ext_vector_type(4))) float f32x4;
typedef __attribute__((ext_vector_type(4))) unsigned int u32x4;
typedef __attribute__((ext_vector_type(2))) unsigned int u32x2;

__device__ __forceinline__ unsigned short f2bf(float f) {
    unsigned int u = __builtin_bit_cast(unsigned int, f);
    u += 0x7fffu + ((u >> 16) & 1u);
    return (unsigned short)(u >> 16);
}
__device__ __forceinline__ float bflo(unsigned int d) {
    return __builtin_bit_cast(float, d << 16);
}
__device__ __forceinline__ float bfhi(unsigned int d) {
    return __builtin_bit_cast(float, d & 0xffff0000u);
}

// ---------------- Kernel 0: w2 [256][1728] f32 -> w2t [1728][256] bf16 (LDS tiled) ----
__global__ __launch_bounds__(256) void prep_w2t(const float* __restrict__ w2,
                                                unsigned short* __restrict__ w2t) {
    __shared__ float t[64][65];
    int kb = blockIdx.x & 3, cb = blockIdx.x >> 2;
    int lc = threadIdx.x & 63, lr = threadIdx.x >> 6;
    #pragma unroll
    for (int i = 0; i < 16; ++i) {
        int kk = lr + i * 4;
        t[kk][lc] = w2[(kb * 64 + kk) * NOUT + cb * 64 + lc];
    }
    __syncthreads();
    #pragma unroll
    for (int i = 0; i < 16; ++i) {
        int cc = lr + i * 4;
        w2t[(cb * 64 + cc) * 256 + kb * 64 + lc] = f2bf(t[lc][cc]);
    }
}

// ---------------- Kernel 1: 5x5 SAME conv + bias + ReLU, 4 outputs/thread ----------------
__global__ __launch_bounds__(256) void conv5_relu_kernel(
    const float* __restrict__ x, const float* __restrict__ cw,
    const float* __restrict__ cb, float* __restrict__ feat)
{
    int idx = blockIdx.x * 256 + threadIdx.x;
    int w4 = (idx & 31) * 4;
    int h  = (idx >> 5) & 127;
    int g  = (idx >> 12) & 63;
    int n  = idx >> 18;
    float bv = cb[g];
    float a[4] = {bv, bv, bv, bv};
    const float* wp = cw + g * 75;
    #pragma unroll
    for (int ci = 0; ci < 3; ++ci) {
        const float* xr = x + (n * 3 + ci) * (HW * HW);
        #pragma unroll
        for (int ki = 0; ki < 5; ++ki) {
            int hh = h + ki - 2;
            if (hh < 0 || hh >= HW) continue;
            const float* row = xr + hh * HW;
            float f[8];
            if (w4 != 0 && w4 != 124) {
                float2 u0 = *(const float2*)(row + w4 - 2);
                float2 u1 = *(const float2*)(row + w4);
                float2 u2 = *(const float2*)(row + w4 + 2);
                float2 u3 = *(const float2*)(row + w4 + 4);
                f[0] = u0.x; f[1] = u0.y; f[2] = u1.x; f[3] = u1.y;
                f[4] = u2.x; f[5] = u2.y; f[6] = u3.x; f[7] = u3.y;
            } else {
                #pragma unroll
                for (int j = 0; j < 8; ++j) {
                    int ww = w4 - 2 + j;
                    f[j] = (ww >= 0 && ww < HW) ? row[ww] : 0.0f;
                }
            }
            float wt[5];
            #pragma unroll
            for (int kj = 0; kj < 5; ++kj) wt[kj] = wp[ci * 25 + ki * 5 + kj];
            #pragma unroll
            for (int j = 0; j < 4; ++j)
                #pragma unroll
                for (int kj = 0; kj < 5; ++kj)
                    a[j] = fmaf(f[j + kj], wt[kj], a[j]);
        }
    }
    float4 o;
    o.x = fmaxf(a[0], 0.f); o.y = fmaxf(a[1], 0.f);
    o.z = fmaxf(a[2], 0.f); o.w = fmaxf(a[3], 0.f);
    *(float4*)&feat[((n * G0n + g) * HW + h) * HW + w4] = o;
}

// ---------------- Kernel 2: producer/consumer fused MFMA + dynamic conv ----------------
// 512 threads: waves 0-3 = producers (MFMA GEMM -> lwc dbuf), waves 4-7 = consumers
// (FT staging + einsum + output). One barrier per chunk iteration.
__global__ __launch_bounds__(512, 2) void fused_metasr_mfma(
    const float* __restrict__ feat, const unsigned short* __restrict__ w2t,
    const float* __restrict__ pos,  const float* __restrict__ w1,
    const float* __restrict__ b1,   const float* __restrict__ b2,
    float* __restrict__ out)
{
    __shared__ __align__(16) unsigned short AL0[64 * 260];   // 33280 B (Ahid ∪ lwc buf0)
    __shared__ __align__(16) unsigned short AL1[64 * 260];   // 33280 B (lwc buf1)
    __shared__ __align__(16) unsigned short FTS[2 * 1536];   //  6144 B (per-chunk feat slabs)

    const int tid = threadIdx.x;
    const int bx = blockIdx.x & 31, by = blockIdx.x >> 5;
    const int oy0 = by * 8, ox0 = bx * 8;
    const int h0 = by * 4,  w0 = bx * 4;

    // ---- hidden = relu(pos @ w1 + b1) -> AL0[px][256] bf16 ----
    {
        int px = tid >> 3, q = tid & 7;
        int rr = (oy0 + (px >> 3)) * OHW + (ox0 + (px & 7));
        float p0 = pos[rr * 3 + 0], p1 = pos[rr * 3 + 1], p2 = pos[rr * 3 + 2];
        #pragma unroll
        for (int j = 0; j < 8; ++j) {
            int k0 = q * 4 + j * 32;
            float4 wa = *(const float4*)&w1[k0];
            float4 wb = *(const float4*)&w1[HID + k0];
            float4 wc = *(const float4*)&w1[2 * HID + k0];
            float4 bb = *(const float4*)&b1[k0];
            unsigned short h0s = f2bf(fmaxf(fmaf(p0, wa.x, fmaf(p1, wb.x, fmaf(p2, wc.x, bb.x))), 0.f));
            unsigned short h1s = f2bf(fmaxf(fmaf(p0, wa.y, fmaf(p1, wb.y, fmaf(p2, wc.y, bb.y))), 0.f));
            unsigned short h2s = f2bf(fmaxf(fmaf(p0, wa.z, fmaf(p1, wb.z, fmaf(p2, wc.z, bb.z))), 0.f));
            unsigned short h3s = f2bf(fmaxf(fmaf(p0, wa.w, fmaf(p1, wb.w, fmaf(p2, wc.w, bb.w))), 0.f));
            u32x2 pk;
            pk.x = (unsigned)h0s | ((unsigned)h1s << 16);
            pk.y = (unsigned)h2s | ((unsigned)h3s << 16);
            *(u32x2*)&AL0[px * 260 + k0] = pk;
        }
    }
    __syncthreads();

    const int wid = tid >> 6;
    if (wid < 4) {
        // ================= PRODUCER =================
        const int lane = tid & 63, cl = lane & 15, hi = lane >> 4;
        const int nq = wid;
        bf16x8 afrag[4][8];
        #pragma unroll
        for (int m = 0; m < 4; ++m)
            #pragma unroll
            for (int k8 = 0; k8 < 8; ++k8)
                afrag[m][k8] = *(const bf16x8*)&AL0[(m * 16 + cl) * 260 + k8 * 32 + hi * 8];

        for (int ch = 0; ch < 10; ++ch) {
            __syncthreads();
            if (ch >= 9) continue;
            unsigned short* lwb = (ch & 1) ? AL1 : AL0;
            f32x4 acc[4][3];
            #pragma unroll
            for (int m = 0; m < 4; ++m)
                #pragma unroll
                for (int j = 0; j < 3; ++j)
                    acc[m][j] = (f32x4){0.f, 0.f, 0.f, 0.f};

            const unsigned short* wp = w2t + (ch * 192 + nq * 48 + cl) * 256 + hi * 8;
            bf16x8 bfr[2][3];
            #pragma unroll
            for (int j = 0; j < 3; ++j)
                bfr[0][j] = *(const bf16x8*)(wp + j * 4096);
            #pragma unroll
            for (int ks = 0; ks < 8; ++ks) {
                if (ks < 7) {
                    #pragma unroll
                    for (int j = 0; j < 3; ++j)
                        bfr[(ks + 1) & 1][j] = *(const bf16x8*)(wp + j * 4096 + (ks + 1) * 32);
                }
                __builtin_amdgcn_s_setprio(1);
                #pragma unroll
                for (int m = 0; m < 4; ++m)
                    #pragma unroll
                    for (int j = 0; j < 3; ++j)
                        acc[m][j] = __builtin_amdgcn_mfma_f32_16x16x32_bf16(
                            afrag[m][ks], bfr[ks & 1][j], acc[m][j], 0, 0, 0);
                __builtin_amdgcn_s_setprio(0);
            }
            // C-write (+bias) into lwc buffer: [px][kt*4+c] bf16
            #pragma unroll
            for (int j = 0; j < 3; ++j) {
                int col = nq * 48 + j * 16 + cl;
                float bv = b2[ch * 192 + col];
                int kt = col / 3;
                int c  = col - kt * 3;
                #pragma unroll
                for (int m = 0; m < 4; ++m)
                    #pragma unroll
                    for (int r = 0; r < 4; ++r)
                        lwb[(m * 16 + hi * 4 + r) * 260 + kt * 4 + c] = f2bf(acc[m][j][r] + bv);
            }
        }
    } else {
        // ================= CONSUMER =================
        const int ctid = tid - 256;
        const int epx = ctid >> 2, en = ctid & 3;
        const int iy = (epx >> 3) >> 1;
        const int ix = (epx & 7) >> 1;
        const bool selhi = (ix >= 2);
        const bool podd  = (ix & 1) != 0;
        float oacc0 = 0.f, oacc1 = 0.f, oacc2 = 0.f;

        for (int ch = 0; ch < 10; ++ch) {
            __syncthreads();
            if (ch < 9) {
                // stage FT slab for chunk ch (ci0..ci0+7) into FTS[ch&1]
                int ci0 = (ch * 64) / 9;
                unsigned short* ftb = FTS + (ch & 1) * 1536;
                for (int i = ctid; i < 1152; i += 256) {
                    int c = i % 6;
                    int n = (i / 6) & 3;
                    int r = (i / 24) % 6;
                    int cidx = i / 144;
                    int ci = ci0 + cidx;
                    int gh = h0 - 1 + r, gw = w0 - 1 + c;
                    float v = 0.0f;
                    if (gh >= 0 && gh < HW && gw >= 0 && gw < HW)
                        v = feat[((n * G0n + ci) * HW + gh) * HW + gw];
                    ftb[((cidx * 6 + r) * 4 + n) * 8 + c] = f2bf(v);
                }
            }
            if (ch >= 1) {
                int cch = ch - 1;
                const unsigned short* lwb = (cch & 1) ? AL1 : AL0;
                const char* ftb = (const char*)(FTS + (cch & 1) * 1536);
                const char* lwp = (const char*)lwb + epx * 520;
                int ci0 = (cch * 64) / 9;
                int k0 = cch * 64;
                int t3a = k0 / 3;
                int t3b = (k0 + 63) / 3;
                auto do_t3 = [&](int t3, bool guard) {
                    int ci = t3 / 3;
                    int di = t3 - ci * 3;
                    const char* fp = ftb + (ci - ci0) * 384 + (iy + di) * 64 + en * 16;
                    u32x4 w = *(const u32x4*)fp;
                    unsigned a0 = selhi ? w.y : w.x;
                    unsigned b0 = selhi ? w.z : w.y;
                    float loa = bflo(a0), hia = bfhi(a0);
                    float lob = bflo(b0), hib = bfhi(b0);
                    float f0 = podd ? hia : loa;
                    float f1 = podd ? lob : hia;
                    float f2 = podd ? hib : lob;
                    int ktb = 3 * t3 - k0;
                    #pragma unroll
                    for (int dj = 0; dj < 3; ++dj) {
                        int kt = ktb + dj;
                        float fv = dj == 0 ? f0 : (dj == 1 ? f1 : f2);
                        if (guard) {
                            fv = ((unsigned)kt < 64u) ? fv : 0.0f;
                            kt = kt < 0 ? 0 : (kt > 63 ? 63 : kt);
                        }
                        u32x2 d = *(const u32x2*)(lwp + (unsigned)(kt * 8));
                        oacc0 = fmaf(fv, bflo(d.x), oacc0);
                        oacc1 = fmaf(fv, bfhi(d.x), oacc1);
                        oacc2 = fmaf(fv, bflo(d.y), oacc2);
                    }
                };
                do_t3(t3a, true);
                for (int t3 = t3a + 1; t3 < t3b; ++t3) do_t3(t3, false);
                do_t3(t3b, true);
            }
        }

        int oy = oy0 + (epx >> 3), ox = ox0 + (epx & 7);
        out[((en * 3 + 0) * OHW + oy) * OHW + ox] = oacc0 + 0.4488f * 255.0f;
        out[((en * 3 + 1) * OHW + oy) * OHW + ox] = oacc1 + 0.4371f * 255.0f;
        out[((en * 3 + 2) * OHW + oy) * OHW + ox] = oacc2 + 0.4040f * 255.0f;
    }
}

extern "C" void kernel_launch(void* const* d_in, const int* in_sizes, int n_in,
                              void* d_out, int out_size, void* d_ws, size_t ws_size,
                              hipStream_t stream) {
    (void)in_sizes; (void)n_in; (void)out_size; (void)ws_size;
    const float* x      = (const float*)d_in[0];
    const float* posm   = (const float*)d_in[1];
    const float* conv_w = (const float*)d_in[2];
    const float* conv_b = (const float*)d_in[3];
    const float* w1     = (const float*)d_in[4];
    const float* b1     = (const float*)d_in[5];
    const float* w2     = (const float*)d_in[6];
    const float* b2     = (const float*)d_in[7];
    float* out = (float*)d_out;

    unsigned short* w2t = (unsigned short*)d_ws;                 // 884736 B
    float* feat = (float*)((char*)d_ws + 884736);                // 16.8 MB

    prep_w2t<<<108, 256, 0, stream>>>(w2, w2t);
    conv5_relu_kernel<<<(NB * G0n * HW * 32) / 256, 256, 0, stream>>>(x, conv_w, conv_b, feat);
    fused_metasr_mfma<<<1024, 512, 0, stream>>>(feat, w2t, posm, w1, b1, b2, out);
}